// Round 3
// baseline (239.358 us; speedup 1.0000x reference)
//
#include <hip/hip_runtime.h>

// out[b,k] = sum_l max_m dot(ctx[b,k,l,:], ent[b,k,m,:])
// ctx = context[:,:,0,:,:], ent = context[:,:,1,:,:]
// BATCH=8 TOP_K=64 MAX_LEN=256 EMB_DIM=768, fp32 in, fp32 out (8x64=512)
//
// R3: BK=128 (512B-contiguous per-row reads), B single-buffered in LDS
//     (70.7KB -> 2 blocks/CU), 2 lgkm-only barriers/step, global loads
//     always in flight across barriers. A stays global->reg->frag.
//     f32->bf16 via native casts (v_cvt_pk_bf16_f32).

#define MAXLEN 256
#define EMB 768
#define BK 128
#define NSTEP 6
#define LSTRIDE 138  // 128 + 10 pad shorts -> 276B row stride (69 dwords, odd)

typedef __attribute__((ext_vector_type(4))) float f32x4;
typedef __attribute__((ext_vector_type(8))) short short8;
typedef __bf16 bf16x8 __attribute__((ext_vector_type(8)));
typedef __bf16 bf16x4 __attribute__((ext_vector_type(4)));

__device__ inline bf16x8 cvt8(float4 a, float4 b) {
  bf16x8 r;
  r[0] = (__bf16)a.x; r[1] = (__bf16)a.y; r[2] = (__bf16)a.z; r[3] = (__bf16)a.w;
  r[4] = (__bf16)b.x; r[5] = (__bf16)b.y; r[6] = (__bf16)b.z; r[7] = (__bf16)b.w;
  return r;
}

__device__ inline uint2 cvt4u(float4 v) {
  union { uint2 u; bf16x4 h; } r;
  r.h[0] = (__bf16)v.x; r.h[1] = (__bf16)v.y;
  r.h[2] = (__bf16)v.z; r.h[3] = (__bf16)v.w;
  return r.u;
}

__global__ __launch_bounds__(512, 2) void som_rowmax_kernel(
    const float* __restrict__ ctx_all, float* __restrict__ out) {
  __shared__ __align__(16) short lsB[MAXLEN][LSTRIDE];
  __shared__ float red[8];

  const int t    = threadIdx.x;
  const int w    = t >> 6;      // wave 0..7
  const int lane = t & 63;
  const int qw   = lane >> 4;   // quarter-wave 0..3
  const int lr   = lane & 15;

  const size_t p = blockIdx.x;  // b*64 + k
  const float* ctx = ctx_all + p * (size_t)(2 * MAXLEN * EMB);
  const float* ent = ctx + (size_t)(MAXLEN * EMB);

  // B staging: 16 rounds x (16 rows x 32 lanes x float4) covers 256x128 f32.
  // One instruction = 2 rows x 512B fully contiguous.
  const int srow = t >> 5;         // 0..15
  const int scol = (t & 31) * 4;   // 0,4,...,124
  const float* gB = ent + (size_t)srow * EMB + scol;

  // A fragment geometry: wave w owns tile-rows 2w, 2w+1 (A rows 32w..32w+31)
  const float* gA0 = ctx + (size_t)(32 * w + lr) * EMB + qw * 8;
  const float* gA1 = ctx + (size_t)(32 * w + 16 + lr) * EMB + qw * 8;

  f32x4 acc[2][16];
#pragma unroll
  for (int h = 0; h < 2; ++h)
#pragma unroll
    for (int mt = 0; mt < 16; ++mt)
      acc[h][mt] = (f32x4){0.f, 0.f, 0.f, 0.f};

  float4 rb[16];        // B(s+1) in flight
  float4 raA[16];       // A(s+1) in flight: [tile*8 + kh*2 + half]
  bf16x8 afr[2][4];     // A(s) fragments (tile, kh)

  auto issueB = [&](int s, int h) {  // half h: rounds 8h..8h+7
#pragma unroll
    for (int r = 0; r < 8; ++r)
      rb[h * 8 + r] = *(const float4*)(gB + (size_t)(h * 8 + r) * (16 * EMB) + s * BK);
  };
  auto commitB = [&]() {
#pragma unroll
    for (int r = 0; r < 16; ++r) {
      const int row = r * 16 + srow;
      *(uint2*)&lsB[row][scol] = cvt4u(rb[r]);
    }
  };
  auto issueA = [&](int s, int h) {  // half h: kh = 2h, 2h+1
#pragma unroll
    for (int kk = 0; kk < 2; ++kk) {
      const int kh = 2 * h + kk;
#pragma unroll
      for (int half = 0; half < 2; ++half) {
        raA[0 * 8 + kh * 2 + half] = *(const float4*)(gA0 + s * BK + kh * 32 + half * 4);
        raA[1 * 8 + kh * 2 + half] = *(const float4*)(gA1 + s * BK + kh * 32 + half * 4);
      }
    }
  };
  auto packA = [&]() {
#pragma unroll
    for (int tile = 0; tile < 2; ++tile)
#pragma unroll
      for (int kh = 0; kh < 4; ++kh)
        afr[tile][kh] = cvt8(raA[tile * 8 + kh * 2 + 0], raA[tile * 8 + kh * 2 + 1]);
  };
  auto mfmaStep = [&]() {
#pragma unroll
    for (int kh = 0; kh < 4; ++kh) {
      const int kq = kh * 32 + qw * 8;
#pragma unroll
      for (int mt = 0; mt < 16; ++mt) {
        bf16x8 bfr = __builtin_bit_cast(bf16x8, *(const short8*)&lsB[mt * 16 + lr][kq]);
        acc[0][mt] = __builtin_amdgcn_mfma_f32_16x16x32_bf16(afr[0][kh], bfr, acc[0][mt], 0, 0, 0);
        acc[1][mt] = __builtin_amdgcn_mfma_f32_16x16x32_bf16(afr[1][kh], bfr, acc[1][mt], 0, 0, 0);
      }
    }
  };
  // barrier that does NOT drain vmcnt: global loads stay in flight across it
  auto barrier = [&]() {
    asm volatile("s_waitcnt lgkmcnt(0)" ::: "memory");
    __builtin_amdgcn_sched_barrier(0);
    __builtin_amdgcn_s_barrier();
    __builtin_amdgcn_sched_barrier(0);
  };

  // ---- prologue: stage step 0, issue step 1's B ----
  issueB(0, 0);
  issueB(0, 1);
  commitB();          // waits B(0)
  issueA(0, 0);
  issueA(0, 1);
  issueB(1, 0);
  issueB(1, 1);
  packA();            // waits A(0); B(1) stays in flight
  barrier();

  // ---- steady state ----
  for (int s = 0; s < NSTEP - 1; ++s) {
    mfmaStep();               // compute step s (lsB holds B(s), afr holds A(s))
    barrier();                // all waves done reading lsB
    issueA(s + 1, 0);         // A half1 in flight before commit's vmcnt waits
    commitB();                // B(s+1) -> lsB (waits rb; A-h1 outstanding)
    issueA(s + 1, 1);
    if (s + 2 < NSTEP) issueB(s + 2, 0);
    packA();                  // waits A(s+1); B(s+2)-h1 outstanding
    if (s + 2 < NSTEP) issueB(s + 2, 1);
    barrier();                // lgkm only; B(s+2) in flight across it
  }
  mfmaStep();                 // final step

  // ---- epilogue: rowmax over m (256 cols), then sum over rows ----
  // C/D layout (16x16x32): col = lane&15, row = (lane>>4)*4 + reg
  float s = 0.f;
#pragma unroll
  for (int h = 0; h < 2; ++h) {
#pragma unroll
    for (int i = 0; i < 4; ++i) {
      float m = acc[h][0][i];
#pragma unroll
      for (int mt = 1; mt < 16; ++mt) m = fmaxf(m, acc[h][mt][i]);
#pragma unroll
      for (int d = 1; d < 16; d <<= 1) m = fmaxf(m, __shfl_xor(m, d, 64));
      s += m;
    }
  }
  s += __shfl_xor(s, 16, 64);
  s += __shfl_xor(s, 32, 64);

  if (lane == 0) red[w] = s;
  __syncthreads();
  if (t == 0) {
    float tot = 0.f;
#pragma unroll
    for (int i = 0; i < 8; ++i) tot += red[i];
    out[p] = tot;
  }
}

extern "C" void kernel_launch(void* const* d_in, const int* in_sizes, int n_in,
                              void* d_out, int out_size, void* d_ws, size_t ws_size,
                              hipStream_t stream) {
  const float* ctx_all = (const float*)d_in[0];
  float* out = (float*)d_out;
  som_rowmax_kernel<<<dim3(512), dim3(512), 0, stream>>>(ctx_all, out);
}

// Round 4
// 226.026 us; speedup vs baseline: 1.0590x; 1.0590x over previous
//
#include <hip/hip_runtime.h>

// out[b,k] = sum_l max_m dot(ctx[b,k,l,:], ent[b,k,m,:])
// ctx = context[:,:,0,:,:], ent = context[:,:,1,:,:]
// BATCH=8 TOP_K=64 MAX_LEN=256 EMB_DIM=768, fp32 in, fp32 out (8x64=512)
//
// R4: BK=128 (512B-contiguous DRAM chunks) with HALF-ROW B panels so the
//     LDS stays double-buffered (2 x 128rows x 128cols bf16 = 69.6KB,
//     2 blocks/CU). 12 stages (6 K-steps x 2 row-halves), one lgkm-only
//     barrier per stage, >=16 global loads/lane in flight across barriers.
//     Registers capped ~250: rb[8] consume-then-refill, raA[8] half-issues,
//     two afr sets alternating per K-step (partial liveness overlap only).

#define MAXLEN 256
#define EMB 768
#define NKB 6            // K-steps of 128
#define NSTAGE 12        // NKB * 2 row-halves
#define LSTRIDE 136      // 128 + 8 pad shorts -> 272B row stride

typedef __attribute__((ext_vector_type(4))) float f32x4;
typedef __attribute__((ext_vector_type(8))) short short8;
typedef __bf16 bf16x8 __attribute__((ext_vector_type(8)));
typedef __bf16 bf16x4 __attribute__((ext_vector_type(4)));

__device__ inline bf16x8 cvt8(float4 a, float4 b) {
  bf16x8 r;
  r[0] = (__bf16)a.x; r[1] = (__bf16)a.y; r[2] = (__bf16)a.z; r[3] = (__bf16)a.w;
  r[4] = (__bf16)b.x; r[5] = (__bf16)b.y; r[6] = (__bf16)b.z; r[7] = (__bf16)b.w;
  return r;
}

__device__ inline uint2 cvt4u(float4 v) {
  union { uint2 u; bf16x4 h; } r;
  r.h[0] = (__bf16)v.x; r.h[1] = (__bf16)v.y;
  r.h[2] = (__bf16)v.z; r.h[3] = (__bf16)v.w;
  return r.u;
}

__global__ __launch_bounds__(512, 2) void som_rowmax_kernel(
    const float* __restrict__ ctx_all, float* __restrict__ out) {
  __shared__ __align__(16) short lsB[2][128][LSTRIDE];
  __shared__ float red[8];

  const int t    = threadIdx.x;
  const int w    = t >> 6;      // wave 0..7
  const int lane = t & 63;
  const int qw   = lane >> 4;   // quarter-wave 0..3
  const int lr   = lane & 15;

  const size_t p = blockIdx.x;  // b*64 + k
  const float* ctx = ctx_all + p * (size_t)(2 * MAXLEN * EMB);
  const float* ent = ctx + (size_t)(MAXLEN * EMB);

  // B staging: panel(kb,h) = rows 128h..128h+127, cols kb*128..+127.
  // Wave instr = 2 rows x 512B fully contiguous.
  const int br = t >> 5;         // 0..15
  const int bc = (t & 31) * 4;   // float col 0,4,...,124
  const float* gB = ent + (size_t)br * EMB + bc;

  // A fragments: wave w owns sim rows 32w..32w+31 (two 16-row tiles)
  const float* gA0 = ctx + (size_t)(32 * w + lr) * EMB + qw * 8;
  const float* gA1 = ctx + (size_t)(32 * w + 16 + lr) * EMB + qw * 8;

  f32x4 acc[2][16];
  float4 rb[8];          // B panel staging (consume-then-refill)
  float4 raA[8];         // A half-issue in flight: [tile*4 + kk*2 + half]
  bf16x8 afr[2][2][4];   // [set][tile][kh], sets alternate per kb

  auto issueB = [&](int kb, int h) {
#pragma unroll
    for (int j = 0; j < 8; ++j)
      rb[j] = *(const float4*)(gB + (size_t)(h * 128 + j * 16) * EMB + kb * 128);
  };
  auto commitB = [&](int buf) {
#pragma unroll
    for (int j = 0; j < 8; ++j)
      *(uint2*)&lsB[buf][br + 16 * j][bc] = cvt4u(rb[j]);
  };
  auto issueA = [&](int kb, int hh) {  // kh pair 2hh, 2hh+1
#pragma unroll
    for (int tile = 0; tile < 2; ++tile)
#pragma unroll
      for (int kk = 0; kk < 2; ++kk) {
        const int kh = 2 * hh + kk;
        const float* g = tile ? gA1 : gA0;
        raA[tile * 4 + kk * 2 + 0] = *(const float4*)(g + kb * 128 + kh * 32 + 0);
        raA[tile * 4 + kk * 2 + 1] = *(const float4*)(g + kb * 128 + kh * 32 + 4);
      }
  };
  auto packA = [&](int set, int hh) {
#pragma unroll
    for (int tile = 0; tile < 2; ++tile)
#pragma unroll
      for (int kk = 0; kk < 2; ++kk)
        afr[set][tile][2 * hh + kk] =
            cvt8(raA[tile * 4 + kk * 2 + 0], raA[tile * 4 + kk * 2 + 1]);
  };
  auto mfmaStage = [&](int set, int h) {
#pragma unroll
    for (int kh = 0; kh < 4; ++kh) {
      const int kq = kh * 32 + qw * 8;
#pragma unroll
      for (int j = 0; j < 8; ++j) {
        bf16x8 bfr = __builtin_bit_cast(bf16x8, *(const short8*)&lsB[h][j * 16 + lr][kq]);
        acc[0][8 * h + j] = __builtin_amdgcn_mfma_f32_16x16x32_bf16(
            afr[set][0][kh], bfr, acc[0][8 * h + j], 0, 0, 0);
        acc[1][8 * h + j] = __builtin_amdgcn_mfma_f32_16x16x32_bf16(
            afr[set][1][kh], bfr, acc[1][8 * h + j], 0, 0, 0);
      }
    }
  };
  // barrier that does NOT drain vmcnt: global loads stay in flight across it
  auto barrier = [&]() {
    asm volatile("s_waitcnt lgkmcnt(0)" ::: "memory");
    __builtin_amdgcn_sched_barrier(0);
    __builtin_amdgcn_s_barrier();
    __builtin_amdgcn_sched_barrier(0);
  };

  // ---- prologue ----
  issueB(0, 0);          // panel 0
  issueA(0, 0);          // kh01 of kb=0
  commitB(0);            // waits rb (raA stays in flight)
  issueB(0, 1);          // panel 1
  packA(0, 0);           // waits raA (panel-1 B stays in flight)
  issueA(0, 1);          // kh23 of kb=0
#pragma unroll
  for (int ti = 0; ti < 2; ++ti)
#pragma unroll
    for (int mt = 0; mt < 16; ++mt)
      acc[ti][mt] = (f32x4){0.f, 0.f, 0.f, 0.f};
  barrier();

  // ---- 12 stages, fully unrolled (static indices everywhere) ----
#pragma unroll
  for (int u = 0; u < NSTAGE; ++u) {
    const int kb = u >> 1, h = u & 1, C = kb & 1;
    if (u + 1 < NSTAGE) commitB((u + 1) & 1);        // waits rb (oldest)
    if (h == 0)          packA(C, 1);                 // kh23(kb): needed now
    else if (kb + 1 < NKB) packA(C ^ 1, 0);           // kh01(kb+1) -> other set
    if (u + 2 < NSTAGE) issueB((u + 2) >> 1, (u + 2) & 1);
    if (kb + 1 < NKB) {
      if (h == 0) issueA(kb + 1, 0);                  // kh01(kb+1)
      else        issueA(kb + 1, 1);                  // kh23(kb+1)
    }
    mfmaStage(C, h);
    if (u + 1 < NSTAGE) barrier();                    // B+A still in flight
  }

  // ---- epilogue: rowmax over m (256 cols), then sum over rows ----
  // C/D layout (16x16x32): col = lane&15, row = (lane>>4)*4 + reg
  float s = 0.f;
#pragma unroll
  for (int ti = 0; ti < 2; ++ti) {
#pragma unroll
    for (int i = 0; i < 4; ++i) {
      float m = acc[ti][0][i];
#pragma unroll
      for (int mt = 1; mt < 16; ++mt) m = fmaxf(m, acc[ti][mt][i]);
#pragma unroll
      for (int d = 1; d < 16; d <<= 1) m = fmaxf(m, __shfl_xor(m, d, 64));
      s += m;
    }
  }
  s += __shfl_xor(s, 16, 64);
  s += __shfl_xor(s, 32, 64);

  if (lane == 0) red[w] = s;
  __syncthreads();
  if (t == 0) {
    float tot = 0.f;
#pragma unroll
    for (int i = 0; i < 8; ++i) tot += red[i];
    out[p] = tot;
  }
}

extern "C" void kernel_launch(void* const* d_in, const int* in_sizes, int n_in,
                              void* d_out, int out_size, void* d_ws, size_t ws_size,
                              hipStream_t stream) {
  const float* ctx_all = (const float*)d_in[0];
  float* out = (float*)d_out;
  som_rowmax_kernel<<<dim3(512), dim3(512), 0, stream>>>(ctx_all, out);
}

// Round 5
// 153.408 us; speedup vs baseline: 1.5603x; 1.4734x over previous
//
#include <hip/hip_runtime.h>

// out[b,k] = sum_l max_m dot(ctx[b,k,l,:], ent[b,k,m,:])
// ctx = context[:,:,0,:,:], ent = context[:,:,1,:,:]
// BATCH=8 TOP_K=64 MAX_LEN=256 EMB_DIM=768, fp32 in, fp32 out (8x64=512)
//
// R5: R2 structure at DOUBLE occupancy. 1024-thread blocks (16 waves),
//     each wave owns ONE 16-row strip -> acc 64 VGPR, total ~125 <= 128
//     => 16 waves/CU (vs R2's 8). BK=64, B double-buffered in LDS,
//     lgkm-only barriers, >=4 B-loads in flight across every barrier.

#define MAXLEN 256
#define EMB 768
#define BK 64
#define NSTEP 12
#define LSTRIDE 72  // 64 + 8 pad shorts -> 144B row stride

typedef __attribute__((ext_vector_type(4))) float f32x4;
typedef __attribute__((ext_vector_type(8))) short short8;
typedef __bf16 bf16x8 __attribute__((ext_vector_type(8)));
typedef __bf16 bf16x4 __attribute__((ext_vector_type(4)));

__device__ inline bf16x8 cvt8(float4 a, float4 b) {
  bf16x8 r;
  r[0] = (__bf16)a.x; r[1] = (__bf16)a.y; r[2] = (__bf16)a.z; r[3] = (__bf16)a.w;
  r[4] = (__bf16)b.x; r[5] = (__bf16)b.y; r[6] = (__bf16)b.z; r[7] = (__bf16)b.w;
  return r;
}

__device__ inline uint2 cvt4u(float4 v) {
  union { uint2 u; bf16x4 h; } r;
  r.h[0] = (__bf16)v.x; r.h[1] = (__bf16)v.y;
  r.h[2] = (__bf16)v.z; r.h[3] = (__bf16)v.w;
  return r.u;
}

__global__ __launch_bounds__(1024, 4) void som_rowmax_kernel(
    const float* __restrict__ ctx_all, float* __restrict__ out) {
  __shared__ __align__(16) short lsB[2][MAXLEN][LSTRIDE];
  __shared__ float red[16];

  const int t    = threadIdx.x;
  const int w    = t >> 6;      // wave 0..15
  const int lane = t & 63;
  const int qw   = lane >> 4;   // quarter-wave 0..3
  const int lr   = lane & 15;

  const size_t p = blockIdx.x;  // b*64 + k
  const float* ctx = ctx_all + p * (size_t)(2 * MAXLEN * EMB);
  const float* ent = ctx + (size_t)(MAXLEN * EMB);

  // B staging: 4 rounds x (64 rows x 16 lanes x float4) covers 256x64 f32
  const int srow = t >> 4;         // 0..63
  const int scol = (t & 15) * 4;   // f32 col 0,4,...,60
  const float* gB = ent + (size_t)srow * EMB + scol;

  // A: wave w owns sim rows 16w..16w+15; lane holds A row 16w+lr
  const float* gA = ctx + (size_t)(16 * w + lr) * EMB + qw * 8;

  f32x4 acc[16];
  float4 rb[4];       // B(s+1) in flight
  float4 ra0[2];      // A(s+1) kh=0 in flight
  float4 ra1[2];      // A(s+1) kh=1 in flight
  bf16x8 afr[2];      // A(s) fragments

  auto issueB = [&](int s) {
#pragma unroll
    for (int j = 0; j < 4; ++j)
      rb[j] = *(const float4*)(gB + (size_t)j * (64 * EMB) + s * BK);
  };
  auto commitB = [&](int buf) {
#pragma unroll
    for (int j = 0; j < 4; ++j)
      *(uint2*)&lsB[buf][j * 64 + srow][scol] = cvt4u(rb[j]);
  };
  auto issueA0 = [&](int s) {
    ra0[0] = *(const float4*)(gA + s * BK + 0);
    ra0[1] = *(const float4*)(gA + s * BK + 4);
  };
  auto issueA1 = [&](int s) {
    ra1[0] = *(const float4*)(gA + s * BK + 32);
    ra1[1] = *(const float4*)(gA + s * BK + 36);
  };
  auto packA0 = [&]() { afr[0] = cvt8(ra0[0], ra0[1]); };
  auto packA1 = [&]() { afr[1] = cvt8(ra1[0], ra1[1]); };
  auto mfmaHalf = [&](int buf, int kh) {
    const int kq = kh * 32 + qw * 8;
#pragma unroll
    for (int mt = 0; mt < 16; ++mt) {
      bf16x8 bfr = __builtin_bit_cast(bf16x8, *(const short8*)&lsB[buf][mt * 16 + lr][kq]);
      acc[mt] = __builtin_amdgcn_mfma_f32_16x16x32_bf16(afr[kh], bfr, acc[mt], 0, 0, 0);
    }
  };
  // barrier that does NOT drain vmcnt: global loads stay in flight across it
  auto barrier = [&]() {
    asm volatile("s_waitcnt lgkmcnt(0)" ::: "memory");
    __builtin_amdgcn_sched_barrier(0);
    __builtin_amdgcn_s_barrier();
    __builtin_amdgcn_sched_barrier(0);
  };

  // ---- prologue ----
  issueB(0);
  issueA0(0);
  issueA1(0);
  commitB(0);          // waits rb=B(0); A(0) pair stays in flight
  issueB(1);
#pragma unroll
  for (int mt = 0; mt < 16; ++mt) acc[mt] = (f32x4){0.f, 0.f, 0.f, 0.f};
  packA0();            // waits A(0)kh0; B(1)+A(0)kh1 in flight
  packA1();            // waits A(0)kh1; B(1) in flight
  barrier();

  // ---- steady state: s = 0..NSTEP-2 ----
  for (int s = 0; s < NSTEP - 1; ++s) {
    issueA0(s + 1);
    issueA1(s + 1);
    commitB((s + 1) & 1);       // waits rb=B(s+1); A(s+1) pair in flight
    if (s + 2 < NSTEP) issueB(s + 2);
    mfmaHalf(s & 1, 0);         // consume afr[0] = A(s) kh0
    mfmaHalf(s & 1, 1);         // consume afr[1] = A(s) kh1
    packA0();                   // waits A(s+1)kh0; B(s+2)+A(s+1)kh1 in flight
    packA1();                   // waits A(s+1)kh1; B(s+2) in flight
    barrier();                  // lgkm only; B(s+2) rides across
  }
  // ---- final step ----
  mfmaHalf((NSTEP - 1) & 1, 0);
  mfmaHalf((NSTEP - 1) & 1, 1);

  // ---- epilogue: rowmax over m (256 cols), then sum over rows ----
  // C/D layout (16x16x32): col = lane&15, row = (lane>>4)*4 + reg
  float s = 0.f;
#pragma unroll
  for (int i = 0; i < 4; ++i) {
    float m = acc[0][i];
#pragma unroll
    for (int mt = 1; mt < 16; ++mt) m = fmaxf(m, acc[mt][i]);
#pragma unroll
    for (int d = 1; d < 16; d <<= 1) m = fmaxf(m, __shfl_xor(m, d, 64));
    s += m;
  }
  // qw-groups hold disjoint row quartets; sum across groups
  s += __shfl_xor(s, 16, 64);
  s += __shfl_xor(s, 32, 64);

  if (lane == 0) red[w] = s;
  __syncthreads();
  if (t == 0) {
    float tot = 0.f;
#pragma unroll
    for (int i = 0; i < 16; ++i) tot += red[i];
    out[p] = tot;
  }
}

extern "C" void kernel_launch(void* const* d_in, const int* in_sizes, int n_in,
                              void* d_out, int out_size, void* d_ws, size_t ws_size,
                              hipStream_t stream) {
  const float* ctx_all = (const float*)d_in[0];
  float* out = (float*)d_out;
  som_rowmax_kernel<<<dim3(512), dim3(1024), 0, stream>>>(ctx_all, out);
}